// Round 6
// baseline (76.383 us; speedup 1.0000x reference)
//
#include <hip/hip_runtime.h>

#define H 1024
#define N 64
#define L 2048
#define TPB 256
#define KK 4              // l-positions per thread; 2 blocks per h
#define NBLK (H * 2)

#define INV2PI 0.15915494309189535f

typedef float f32x2 __attribute__((ext_vector_type(2)));

// complex multiply r = w * s, layout (re, im) = (lo, hi). Verified R1-R5.
// t = (w.re*s.re, w.im*s.re); r = (t.lo - w.im*s.im, t.hi + w.re*s.im)
__device__ __forceinline__ f32x2 cmul(f32x2 w, f32x2 s) {
    f32x2 t, r;
    asm("v_pk_mul_f32 %0, %1, %2 op_sel_hi:[1,0]"
        : "=v"(t) : "v"(w), "v"(s));
    asm("v_pk_fma_f32 %0, %1, %2, %3 op_sel:[1,1,0] op_sel_hi:[0,1,1] neg_lo:[1,0,0]"
        : "=v"(r) : "v"(w), "v"(s), "v"(t));
    return r;
}

__device__ __forceinline__ f32x2 cexp_rev(float mag_arg, float rev_arg) {
    // exp(mag_arg) * (cos(2*pi*rev_arg), sin(2*pi*rev_arg))
    float m = __expf(mag_arg);
    float rv = rev_arg - floorf(rev_arg);
    f32x2 e;
    e.x = m * __builtin_amdgcn_cosf(rv);
    e.y = m * __builtin_amdgcn_sinf(rv);
    return e;
}

// 2 blocks per h: block handles l in [half*1024, half*1024+1024).
// Thread t owns l = half*1024 + t + 256k, k=0..3.
// Phase 1 tables (per block):
//   W16[n][j] = cm[n] * exp(dtA*(16j + 1024*half))   (j<16)
//   E1 [n][j] = exp(dtA*j)                           (j<16)
//   S  [n]    = exp(dtA*256)
// Phase 2 (trans-free): w0 = W16[n][t>>4] * E1[n][t&15]; 4 steps of w *= S[n],
// accumulating ONLY Re(w) (scalar f32 accs — im accumulation is dead work).
__global__ __launch_bounds__(TPB, 8) void s4d_fused(const float* __restrict__ log_dt,
                                                    const float* __restrict__ Cv,
                                                    const float* __restrict__ Av,
                                                    float* __restrict__ out)
{
    __shared__ f32x2 W16[N][16];   // 8 KB
    __shared__ f32x2 E1t[N][16];   // 8 KB
    __shared__ f32x2 Sv[N];        // 512 B

    const int b    = blockIdx.x;
    const int h    = b >> 1;
    const int half = b & 1;
    const int t    = threadIdx.x;

    // ---------- phase 1: tables ----------
    {
        const int n  = t >> 2;          // 4 threads per n
        const int j0 = (t & 3) << 2;    // each computes 4 j's
        float dt = __expf(log_dt[h]);

        float2 a2 = ((const float2*)Av)[n];
        float dr    = dt * a2.x;
        float direv = dt * a2.y * INV2PI;   // phase in revolutions per l

        // cm = 2 * C * (exp(dtA) - 1) / A
        f32x2 r1 = cexp_rev(dr, direv);
        float2 c2 = ((const float2*)Cv)[h * N + n];
        float er = r1.x - 1.0f, ei = r1.y;
        float tr = c2.x * er - c2.y * ei;
        float ti = c2.x * ei + c2.y * er;
        float inv = 2.0f / (a2.x * a2.x + a2.y * a2.y);
        f32x2 cm;
        cm.x = (tr * a2.x + ti * a2.y) * inv;
        cm.y = (ti * a2.x - tr * a2.y) * inv;

        const float off = (float)(half << 10);   // 0 or 1024
#pragma unroll
        for (int jj = 0; jj < 4; ++jj) {
            float fj = (float)(j0 + jj);
            E1t[n][j0 + jj] = cexp_rev(dr * fj, direv * fj);
            float fg = fj * 16.0f + off;
            W16[n][j0 + jj] = cmul(cexp_rev(dr * fg, direv * fg), cm);
        }

        if (t < N) {                     // S[t] = exp(dtA[t]*256)
            float2 a2b = ((const float2*)Av)[t];
            float drb = dt * a2b.x;
            float dib = dt * a2b.y * INV2PI;
            Sv[t] = cexp_rev(drb * 256.0f, dib * 256.0f);
        }
    }
    __syncthreads();

    // ---------- phase 2: trans-free recurrence, scalar re-accumulate ----------
    float acc[KK];
#pragma unroll
    for (int k = 0; k < KK; ++k) acc[k] = 0.0f;

    const int jhi = t >> 4;    // W16 index (broadcast within 16-lane groups)
    const int jlo = t & 15;    // E1 index (16 distinct 8B entries, conflict-free)

#pragma unroll 2
    for (int n = 0; n < N; ++n) {
        f32x2 w16 = W16[n][jhi];
        f32x2 e1  = E1t[n][jlo];
        f32x2 s   = Sv[n];
        f32x2 w = cmul(e1, w16);       // w0 = cm * exp(dtA * l0)

#pragma unroll
        for (int k = 0; k < KK; ++k) {
            acc[k] += w.x;             // scalar v_add_f32; im never accumulated
            w = cmul(w, s);            // last iteration DCE'd (non-volatile asm)
        }
    }

    float* o = out + h * L + (half << 10) + t;
#pragma unroll
    for (int k = 0; k < KK; ++k) o[k * TPB] = acc[k];   // coalesced per k
}

extern "C" void kernel_launch(void* const* d_in, const int* in_sizes, int n_in,
                              void* d_out, int out_size, void* d_ws, size_t ws_size,
                              hipStream_t stream) {
    const float* log_dt = (const float*)d_in[0];
    const float* Cv     = (const float*)d_in[1];   // (H, N, 2)
    const float* Av     = (const float*)d_in[2];   // (N, 2)
    float* out          = (float*)d_out;           // (H, L) fp32

    s4d_fused<<<NBLK, TPB, 0, stream>>>(log_dt, Cv, Av, out);
}